// Round 1
// baseline (2119.174 us; speedup 1.0000x reference)
//
#include <hip/hip_runtime.h>
#include <hip/hip_bf16.h>

#define N_NODES 131072
#define N_EDGES 262144
#define NBATCH  16

typedef __attribute__((ext_vector_type(8))) __bf16 bf16x8;
typedef __attribute__((ext_vector_type(4))) float  fx4;

__device__ __forceinline__ fx4 mfma16(bf16x8 a, bf16x8 b, fx4 c) {
    return __builtin_amdgcn_mfma_f32_16x16x32_bf16(a, b, c, 0, 0, 0);
}

__device__ __forceinline__ void ld8(const float* p, fx4& x, fx4& y) {
    const fx4* q = (const fx4*)p;
    x = q[0]; y = q[1];
}
__device__ __forceinline__ bf16x8 cvt8(fx4 a, fx4 b) {
    bf16x8 r;
    r[0] = (__bf16)a[0]; r[1] = (__bf16)a[1]; r[2] = (__bf16)a[2]; r[3] = (__bf16)a[3];
    r[4] = (__bf16)b[0]; r[5] = (__bf16)b[1]; r[6] = (__bf16)b[2]; r[7] = (__bf16)b[3];
    return r;
}

// ---- rearrange row-major fp32 W[K][128] into bf16 MFMA B-operand order ----
// consumer reads bf16x8 at ((t*KS+ks)*64+lane):
//   B[k = ks*32 + (lane>>4)*8 + j][n = t*16 + (lane&15)]
__global__ void gn_swizzle(const float* __restrict__ src, __bf16* __restrict__ dst, int KS)
{
    int idx = blockIdx.x * 256 + threadIdx.x;
    int total = KS * 32 * 128;
    if (idx >= total) return;
    int j    = idx & 7;
    int lane = (idx >> 3) & 63;
    int rem  = idx >> 9;
    int ks   = rem % KS;
    int t    = rem / KS;
    int n = t * 16 + (lane & 15);
    int k = ks * 32 + ((lane >> 4) << 3) + j;
    dst[idx] = (__bf16)src[k * 128 + n];
}

// ---- edge block: u = MLP(concat(edges, nodes[send], nodes[recv], gl[gid])) ----
// Two sequential 16-row passes per wave (halves acc regs + LDS), explicit
// depth-2 A-fragment prefetch, wave-private s_H slice (no inter-GEMM barrier).
// LDS ~19.5 KB -> 8 blocks/CU by LDS; launch_bounds(256,6) -> 24 waves/CU.
__global__ __launch_bounds__(256, 6) void gn_edge_kernel(
    const float* __restrict__ nodes, const float* __restrict__ edges,
    const float* __restrict__ gl,
    const __bf16* __restrict__ W1sw, const float* __restrict__ b1,
    const __bf16* __restrict__ W2sw, const float* __restrict__ b2,
    const float* __restrict__ rn_w,
    const int* __restrict__ senders, const int* __restrict__ receivers,
    const int* __restrict__ egid,
    float* __restrict__ out_edges,
    float* __restrict__ adjacent,
    float* __restrict__ edge_agg)
{
    __shared__ __align__(16) __bf16 s_H[4][16][136];   // 17408 B, wave-private slices
    __shared__ float s_agg[4 * 128];                   // block spans <=4 graphs (sorted gid)

    const int tid  = threadIdx.x;
    const int wave = tid >> 6, lane = tid & 63;
    const int m = lane & 15, q = lane >> 4;
    const int qo = q << 3;
    const int eblock = blockIdx.x * 128;
    const int wbase  = wave * 32;
    const int g0 = egid[eblock];                       // min gid in block (sorted)

    for (int i = tid; i < 4 * 128; i += 256) s_agg[i] = 0.f;
    __syncthreads();

    const bf16x8* W1v = (const bf16x8*)W1sw;
    const bf16x8* W2v = (const bf16x8*)W2sw;
    const float mres = log1pf(expf(rn_w[0]));

    #pragma unroll 1
    for (int p = 0; p < 2; ++p) {
        // ---- this lane's A-row (row m of the 16-row pass tile) ----
        const int e = eblock + wbase + p * 16 + m;
        const float* aseg[4];
        aseg[0] = edges + (size_t)e * 128;
        aseg[1] = nodes + (size_t)senders[e]   * 128;
        aseg[2] = nodes + (size_t)receivers[e] * 128;
        aseg[3] = gl    + (size_t)egid[e]      * 128;

        fx4 acc[8];
        #pragma unroll
        for (int t = 0; t < 8; ++t) acc[t] = fx4{0.f, 0.f, 0.f, 0.f};

        // GEMM1: K=512, 16 k-steps of 32, depth-2 raw prefetch
        fx4 buf[2][2];
        ld8(aseg[0] + qo,      buf[0][0], buf[0][1]);   // ks=0
        ld8(aseg[0] + 32 + qo, buf[1][0], buf[1][1]);   // ks=1
        #pragma unroll
        for (int ks = 0; ks < 16; ++ks) {
            bf16x8 a = cvt8(buf[ks & 1][0], buf[ks & 1][1]);
            if (ks < 14) {
                const int kn = ks + 2;
                ld8(aseg[kn >> 2] + ((kn & 3) << 5) + qo, buf[ks & 1][0], buf[ks & 1][1]);
            }
            #pragma unroll
            for (int t = 0; t < 8; ++t)
                acc[t] = mfma16(a, W1v[(t * 16 + ks) * 64 + lane], acc[t]);
        }

        // bias + relu -> H (bf16) in wave-private LDS slice. C/D map: col=m, row=q*4+r
        #pragma unroll
        for (int t = 0; t < 8; ++t) {
            float bv = b1[t * 16 + m];
            #pragma unroll
            for (int r = 0; r < 4; ++r)
                s_H[wave][q * 4 + r][t * 16 + m] = (__bf16)fmaxf(acc[t][r] + bv, 0.f);
        }
        // no __syncthreads: slice is wave-private; per-wave DS ordering suffices

        #pragma unroll
        for (int t = 0; t < 8; ++t) acc[t] = fx4{0.f, 0.f, 0.f, 0.f};

        // GEMM2: K=128, 4 k-steps
        #pragma unroll
        for (int ks = 0; ks < 4; ++ks) {
            bf16x8 a = *(const bf16x8*)&s_H[wave][m][ks * 32 + qo];
            #pragma unroll
            for (int t = 0; t < 8; ++t)
                acc[t] = mfma16(a, W2v[(t * 4 + ks) * 64 + lane], acc[t]);
        }

        // epilogue: lane (q,m) owns rows q*4+r of this pass tile
        const int er0 = eblock + wbase + p * 16 + q * 4;
        int rcv[4], gd[4];
        #pragma unroll
        for (int r = 0; r < 4; ++r) {
            rcv[r] = receivers[er0 + r];
            gd[r]  = egid[er0 + r];
        }
        const bool sameg = (gd[0] == gd[3]);
        const int rel0 = gd[0] - g0;

        #pragma unroll
        for (int t = 0; t < 8; ++t) {
            const int col = t * 16 + m;
            const float bv = b2[col];
            float usum = 0.f;
            #pragma unroll
            for (int r = 0; r < 4; ++r) {
                const size_t eg = (size_t)(er0 + r);
                float u = acc[t][r] + bv;
                out_edges[eg * 128 + col] = edges[eg * 128 + col] + mres * u;
                unsafeAtomicAdd(&adjacent[(size_t)rcv[r] * 128 + col], u);
                if (sameg) usum += u;
                else {
                    int rel = gd[r] - g0;
                    if (rel < 4) atomicAdd(&s_agg[rel * 128 + col], u);
                    else         unsafeAtomicAdd(&edge_agg[gd[r] * 128 + col], u);
                }
            }
            if (sameg) {
                if (rel0 < 4) atomicAdd(&s_agg[rel0 * 128 + col], usum);
                else          unsafeAtomicAdd(&edge_agg[gd[0] * 128 + col], usum);
            }
        }
    }

    __syncthreads();
    for (int i = tid; i < 4 * 128; i += 256) {
        float v = s_agg[i];
        if (v != 0.f)
            unsafeAtomicAdd(&edge_agg[(g0 + (i >> 7)) * 128 + (i & 127)], v);
    }
}

// ---- node block: u = MLP(concat(nodes, adjacent, gl[gid])) ----
__global__ __launch_bounds__(256, 6) void gn_node_kernel(
    const float* __restrict__ nodes,
    const float* __restrict__ gl,
    const __bf16* __restrict__ W1sw, const float* __restrict__ b1,
    const __bf16* __restrict__ W2sw, const float* __restrict__ b2,
    const float* __restrict__ rn_w,
    const int* __restrict__ ngid,
    const float* __restrict__ adjacent,
    float* __restrict__ out_nodes,
    float* __restrict__ node_agg)
{
    __shared__ __align__(16) __bf16 s_H[4][16][136];
    __shared__ float s_agg[4 * 128];

    const int tid  = threadIdx.x;
    const int wave = tid >> 6, lane = tid & 63;
    const int m = lane & 15, q = lane >> 4;
    const int qo = q << 3;
    const int nblock = blockIdx.x * 128;
    const int wbase  = wave * 32;
    const int g0 = ngid[nblock];

    for (int i = tid; i < 4 * 128; i += 256) s_agg[i] = 0.f;
    __syncthreads();

    const bf16x8* W1v = (const bf16x8*)W1sw;
    const bf16x8* W2v = (const bf16x8*)W2sw;
    const float mres = log1pf(expf(rn_w[0]));

    #pragma unroll 1
    for (int p = 0; p < 2; ++p) {
        const int v = nblock + wbase + p * 16 + m;
        const float* aseg[3];
        aseg[0] = nodes    + (size_t)v * 128;
        aseg[1] = adjacent + (size_t)v * 128;
        aseg[2] = gl       + (size_t)ngid[v] * 128;

        fx4 acc[8];
        #pragma unroll
        for (int t = 0; t < 8; ++t) acc[t] = fx4{0.f, 0.f, 0.f, 0.f};

        // GEMM1: K=384, 12 k-steps, depth-2 raw prefetch
        fx4 buf[2][2];
        ld8(aseg[0] + qo,      buf[0][0], buf[0][1]);
        ld8(aseg[0] + 32 + qo, buf[1][0], buf[1][1]);
        #pragma unroll
        for (int ks = 0; ks < 12; ++ks) {
            bf16x8 a = cvt8(buf[ks & 1][0], buf[ks & 1][1]);
            if (ks < 10) {
                const int kn = ks + 2;
                ld8(aseg[kn >> 2] + ((kn & 3) << 5) + qo, buf[ks & 1][0], buf[ks & 1][1]);
            }
            #pragma unroll
            for (int t = 0; t < 8; ++t)
                acc[t] = mfma16(a, W1v[(t * 12 + ks) * 64 + lane], acc[t]);
        }

        #pragma unroll
        for (int t = 0; t < 8; ++t) {
            float bv = b1[t * 16 + m];
            #pragma unroll
            for (int r = 0; r < 4; ++r)
                s_H[wave][q * 4 + r][t * 16 + m] = (__bf16)fmaxf(acc[t][r] + bv, 0.f);
        }

        #pragma unroll
        for (int t = 0; t < 8; ++t) acc[t] = fx4{0.f, 0.f, 0.f, 0.f};

        #pragma unroll
        for (int ks = 0; ks < 4; ++ks) {
            bf16x8 a = *(const bf16x8*)&s_H[wave][m][ks * 32 + qo];
            #pragma unroll
            for (int t = 0; t < 8; ++t)
                acc[t] = mfma16(a, W2v[(t * 4 + ks) * 64 + lane], acc[t]);
        }

        const int vr0 = nblock + wbase + p * 16 + q * 4;
        int gd[4];
        #pragma unroll
        for (int r = 0; r < 4; ++r) gd[r] = ngid[vr0 + r];
        const bool sameg = (gd[0] == gd[3]);
        const int rel0 = gd[0] - g0;

        #pragma unroll
        for (int t = 0; t < 8; ++t) {
            const int col = t * 16 + m;
            const float bv = b2[col];
            float usum = 0.f;
            #pragma unroll
            for (int r = 0; r < 4; ++r) {
                const size_t vg = (size_t)(vr0 + r);
                float u = acc[t][r] + bv;
                out_nodes[vg * 128 + col] = nodes[vg * 128 + col] + mres * u;
                if (sameg) usum += u;
                else {
                    int rel = gd[r] - g0;
                    if (rel < 4) atomicAdd(&s_agg[rel * 128 + col], u);
                    else         unsafeAtomicAdd(&node_agg[gd[r] * 128 + col], u);
                }
            }
            if (sameg) {
                if (rel0 < 4) atomicAdd(&s_agg[rel0 * 128 + col], usum);
                else          unsafeAtomicAdd(&node_agg[gd[0] * 128 + col], usum);
            }
        }
    }

    __syncthreads();
    for (int i = tid; i < 4 * 128; i += 256) {
        float v = s_agg[i];
        if (v != 0.f)
            unsafeAtomicAdd(&node_agg[(g0 + (i >> 7)) * 128 + (i & 127)], v);
    }
}

// ---- global block: tiny MLP in fp32, 16 blocks x 128 threads ----
__global__ void gn_global_kernel(
    const float* __restrict__ gl,
    const float* __restrict__ gW1, const float* __restrict__ gb1,
    const float* __restrict__ gW2, const float* __restrict__ gb2,
    const float* __restrict__ rn_w,
    const float* __restrict__ node_agg, const float* __restrict__ edge_agg,
    float* __restrict__ out_gl)
{
    __shared__ float s_x[384];
    __shared__ float s_h[128];
    const int row = blockIdx.x, t = threadIdx.x;

    s_x[t]       = node_agg[row * 128 + t];
    s_x[128 + t] = edge_agg[row * 128 + t];
    s_x[256 + t] = gl[row * 128 + t];
    __syncthreads();

    float acc = gb1[t];
    for (int k = 0; k < 384; ++k) acc += s_x[k] * gW1[k * 128 + t];
    s_h[t] = fmaxf(acc, 0.f);
    __syncthreads();

    float acc2 = gb2[t];
    for (int k = 0; k < 128; ++k) acc2 += s_h[k] * gW2[k * 128 + t];
    const float mres = log1pf(expf(rn_w[0]));
    out_gl[row * 128 + t] = gl[row * 128 + t] + mres * acc2;
}

extern "C" void kernel_launch(void* const* d_in, const int* in_sizes, int n_in,
                              void* d_out, int out_size, void* d_ws, size_t ws_size,
                              hipStream_t stream)
{
    const float* nodes = (const float*)d_in[0];
    const float* edges = (const float*)d_in[1];
    const float* gl    = (const float*)d_in[2];
    const float* eW1   = (const float*)d_in[3];
    const float* eb1   = (const float*)d_in[4];
    const float* eW2   = (const float*)d_in[5];
    const float* eb2   = (const float*)d_in[6];
    const float* nW1   = (const float*)d_in[7];
    const float* nb1   = (const float*)d_in[8];
    const float* nW2   = (const float*)d_in[9];
    const float* nb2   = (const float*)d_in[10];
    const float* gW1   = (const float*)d_in[11];
    const float* gb1   = (const float*)d_in[12];
    const float* gW2   = (const float*)d_in[13];
    const float* gb2   = (const float*)d_in[14];
    const float* rn_w  = (const float*)d_in[15];
    const int* receivers = (const int*)d_in[16];
    const int* senders   = (const int*)d_in[17];
    const int* ngid      = (const int*)d_in[18];
    const int* egid      = (const int*)d_in[19];

    char* ws = (char*)d_ws;
    __bf16* eW1sw    = (__bf16*)(ws + 0);                // 131072 B
    __bf16* eW2sw    = (__bf16*)(ws + 131072);           // 32768 B
    __bf16* nW1sw    = (__bf16*)(ws + 163840);           // 98304 B
    __bf16* nW2sw    = (__bf16*)(ws + 262144);           // 32768 B
    float*  edge_agg = (float*)(ws + 294912);            // 8192 B
    float*  node_agg = (float*)(ws + 303104);            // 8192 B
    float*  adjacent = (float*)(ws + 311296);            // 67108864 B

    float* out_nodes = (float*)d_out;
    float* out_edges = out_nodes + (size_t)N_NODES * 128;
    float* out_gl    = out_edges + (size_t)N_EDGES * 128;

    // zero aggs + adjacent (ws is poisoned 0xAA before every launch)
    hipMemsetAsync(ws + 294912, 0, (size_t)16384 + 67108864, stream);

    gn_swizzle<<<dim3(256), dim3(256), 0, stream>>>(eW1, eW1sw, 16);
    gn_swizzle<<<dim3(64),  dim3(256), 0, stream>>>(eW2, eW2sw, 4);
    gn_swizzle<<<dim3(192), dim3(256), 0, stream>>>(nW1, nW1sw, 12);
    gn_swizzle<<<dim3(64),  dim3(256), 0, stream>>>(nW2, nW2sw, 4);

    gn_edge_kernel<<<dim3(N_EDGES / 128), dim3(256), 0, stream>>>(
        nodes, edges, gl, eW1sw, eb1, eW2sw, eb2, rn_w,
        senders, receivers, egid, out_edges, adjacent, edge_agg);

    gn_node_kernel<<<dim3(N_NODES / 128), dim3(256), 0, stream>>>(
        nodes, gl, nW1sw, nb1, nW2sw, nb2, rn_w,
        ngid, adjacent, out_nodes, node_agg);

    gn_global_kernel<<<dim3(NBATCH), dim3(128), 0, stream>>>(
        gl, gW1, gb1, gW2, gb2, rn_w, node_agg, edge_agg, out_gl);
}

// Round 2
// 1948.047 us; speedup vs baseline: 1.0878x; 1.0878x over previous
//
#include <hip/hip_runtime.h>
#include <hip/hip_bf16.h>

#define N_NODES 131072
#define N_EDGES 262144
#define NBATCH  16

typedef __attribute__((ext_vector_type(8))) __bf16 bf16x8;
typedef __attribute__((ext_vector_type(4))) float  fx4;

__device__ __forceinline__ fx4 mfma16(bf16x8 a, bf16x8 b, fx4 c) {
    return __builtin_amdgcn_mfma_f32_16x16x32_bf16(a, b, c, 0, 0, 0);
}

__device__ __forceinline__ void ld8(const float* p, fx4& x, fx4& y) {
    const fx4* q = (const fx4*)p;
    x = q[0]; y = q[1];
}
__device__ __forceinline__ bf16x8 cvt8(fx4 a, fx4 b) {
    bf16x8 r;
    r[0] = (__bf16)a[0]; r[1] = (__bf16)a[1]; r[2] = (__bf16)a[2]; r[3] = (__bf16)a[3];
    r[4] = (__bf16)b[0]; r[5] = (__bf16)b[1]; r[6] = (__bf16)b[2]; r[7] = (__bf16)b[3];
    return r;
}

// ---- rearrange row-major fp32 W[K][128] into bf16 MFMA B-operand order ----
// consumer reads bf16x8 at ((t*KS+ks)*64+lane):
//   B[k = ks*32 + (lane>>4)*8 + j][n = t*16 + (lane&15)]
__global__ void gn_swizzle(const float* __restrict__ src, __bf16* __restrict__ dst, int KS)
{
    int idx = blockIdx.x * 256 + threadIdx.x;
    int total = KS * 32 * 128;
    if (idx >= total) return;
    int j    = idx & 7;
    int lane = (idx >> 3) & 63;
    int rem  = idx >> 9;
    int ks   = rem % KS;
    int t    = rem / KS;
    int n = t * 16 + (lane & 15);
    int k = ks * 32 + ((lane >> 4) << 3) + j;
    dst[idx] = (__bf16)src[k * 128 + n];
}

// ---- edge block: u = MLP(concat(edges, nodes[send], nodes[recv], gl[gid])) ----
// Two sequential 16-row passes per wave (halves acc regs + LDS), explicit
// depth-2 A-fragment prefetch, wave-private s_H slice (no inter-GEMM barrier).
// LDS ~19.5 KB. launch_bounds(256,4): VGPR cap 128 — round 1's (256,6) forced
// VGPR=40 and spilled accumulators to scratch (FETCH 260MB->1.7GB, 6x traffic).
__global__ __launch_bounds__(256, 4) void gn_edge_kernel(
    const float* __restrict__ nodes, const float* __restrict__ edges,
    const float* __restrict__ gl,
    const __bf16* __restrict__ W1sw, const float* __restrict__ b1,
    const __bf16* __restrict__ W2sw, const float* __restrict__ b2,
    const float* __restrict__ rn_w,
    const int* __restrict__ senders, const int* __restrict__ receivers,
    const int* __restrict__ egid,
    float* __restrict__ out_edges,
    float* __restrict__ adjacent,
    float* __restrict__ edge_agg)
{
    __shared__ __align__(16) __bf16 s_H[4][16][136];   // 17408 B, wave-private slices
    __shared__ float s_agg[4 * 128];                   // block spans <=4 graphs (sorted gid)

    const int tid  = threadIdx.x;
    const int wave = tid >> 6, lane = tid & 63;
    const int m = lane & 15, q = lane >> 4;
    const int qo = q << 3;
    const int eblock = blockIdx.x * 128;
    const int wbase  = wave * 32;
    const int g0 = egid[eblock];                       // min gid in block (sorted)

    for (int i = tid; i < 4 * 128; i += 256) s_agg[i] = 0.f;
    __syncthreads();

    const bf16x8* W1v = (const bf16x8*)W1sw;
    const bf16x8* W2v = (const bf16x8*)W2sw;
    const float mres = log1pf(expf(rn_w[0]));

    #pragma unroll 1
    for (int p = 0; p < 2; ++p) {
        // ---- this lane's A-row (row m of the 16-row pass tile) ----
        const int e = eblock + wbase + p * 16 + m;
        const float* aseg[4];
        aseg[0] = edges + (size_t)e * 128;
        aseg[1] = nodes + (size_t)senders[e]   * 128;
        aseg[2] = nodes + (size_t)receivers[e] * 128;
        aseg[3] = gl    + (size_t)egid[e]      * 128;

        fx4 acc[8];
        #pragma unroll
        for (int t = 0; t < 8; ++t) acc[t] = fx4{0.f, 0.f, 0.f, 0.f};

        // GEMM1: K=512, 16 k-steps of 32, depth-2 raw prefetch
        fx4 buf[2][2];
        ld8(aseg[0] + qo,      buf[0][0], buf[0][1]);   // ks=0
        ld8(aseg[0] + 32 + qo, buf[1][0], buf[1][1]);   // ks=1
        #pragma unroll
        for (int ks = 0; ks < 16; ++ks) {
            bf16x8 a = cvt8(buf[ks & 1][0], buf[ks & 1][1]);
            if (ks < 14) {
                const int kn = ks + 2;
                ld8(aseg[kn >> 2] + ((kn & 3) << 5) + qo, buf[ks & 1][0], buf[ks & 1][1]);
            }
            #pragma unroll
            for (int t = 0; t < 8; ++t)
                acc[t] = mfma16(a, W1v[(t * 16 + ks) * 64 + lane], acc[t]);
        }

        // bias + relu -> H (bf16) in wave-private LDS slice. C/D map: col=m, row=q*4+r
        #pragma unroll
        for (int t = 0; t < 8; ++t) {
            float bv = b1[t * 16 + m];
            #pragma unroll
            for (int r = 0; r < 4; ++r)
                s_H[wave][q * 4 + r][t * 16 + m] = (__bf16)fmaxf(acc[t][r] + bv, 0.f);
        }
        // no __syncthreads: slice is wave-private; per-wave DS ordering suffices

        #pragma unroll
        for (int t = 0; t < 8; ++t) acc[t] = fx4{0.f, 0.f, 0.f, 0.f};

        // GEMM2: K=128, 4 k-steps
        #pragma unroll
        for (int ks = 0; ks < 4; ++ks) {
            bf16x8 a = *(const bf16x8*)&s_H[wave][m][ks * 32 + qo];
            #pragma unroll
            for (int t = 0; t < 8; ++t)
                acc[t] = mfma16(a, W2v[(t * 4 + ks) * 64 + lane], acc[t]);
        }

        // epilogue: lane (q,m) owns rows q*4+r of this pass tile
        const int er0 = eblock + wbase + p * 16 + q * 4;
        int rcv[4], gd[4];
        #pragma unroll
        for (int r = 0; r < 4; ++r) {
            rcv[r] = receivers[er0 + r];
            gd[r]  = egid[er0 + r];
        }
        const bool sameg = (gd[0] == gd[3]);
        const int rel0 = gd[0] - g0;

        #pragma unroll
        for (int t = 0; t < 8; ++t) {
            const int col = t * 16 + m;
            const float bv = b2[col];
            float usum = 0.f;
            #pragma unroll
            for (int r = 0; r < 4; ++r) {
                const size_t eg = (size_t)(er0 + r);
                float u = acc[t][r] + bv;
                out_edges[eg * 128 + col] = edges[eg * 128 + col] + mres * u;
                unsafeAtomicAdd(&adjacent[(size_t)rcv[r] * 128 + col], u);
                if (sameg) usum += u;
                else {
                    int rel = gd[r] - g0;
                    if (rel < 4) atomicAdd(&s_agg[rel * 128 + col], u);
                    else         unsafeAtomicAdd(&edge_agg[gd[r] * 128 + col], u);
                }
            }
            if (sameg) {
                if (rel0 < 4) atomicAdd(&s_agg[rel0 * 128 + col], usum);
                else          unsafeAtomicAdd(&edge_agg[gd[0] * 128 + col], usum);
            }
        }
    }

    __syncthreads();
    for (int i = tid; i < 4 * 128; i += 256) {
        float v = s_agg[i];
        if (v != 0.f)
            unsafeAtomicAdd(&edge_agg[(g0 + (i >> 7)) * 128 + (i & 127)], v);
    }
}

// ---- node block: u = MLP(concat(nodes, adjacent, gl[gid])) ----
__global__ __launch_bounds__(256, 4) void gn_node_kernel(
    const float* __restrict__ nodes,
    const float* __restrict__ gl,
    const __bf16* __restrict__ W1sw, const float* __restrict__ b1,
    const __bf16* __restrict__ W2sw, const float* __restrict__ b2,
    const float* __restrict__ rn_w,
    const int* __restrict__ ngid,
    const float* __restrict__ adjacent,
    float* __restrict__ out_nodes,
    float* __restrict__ node_agg)
{
    __shared__ __align__(16) __bf16 s_H[4][16][136];
    __shared__ float s_agg[4 * 128];

    const int tid  = threadIdx.x;
    const int wave = tid >> 6, lane = tid & 63;
    const int m = lane & 15, q = lane >> 4;
    const int qo = q << 3;
    const int nblock = blockIdx.x * 128;
    const int wbase  = wave * 32;
    const int g0 = ngid[nblock];

    for (int i = tid; i < 4 * 128; i += 256) s_agg[i] = 0.f;
    __syncthreads();

    const bf16x8* W1v = (const bf16x8*)W1sw;
    const bf16x8* W2v = (const bf16x8*)W2sw;
    const float mres = log1pf(expf(rn_w[0]));

    #pragma unroll 1
    for (int p = 0; p < 2; ++p) {
        const int v = nblock + wbase + p * 16 + m;
        const float* aseg[3];
        aseg[0] = nodes    + (size_t)v * 128;
        aseg[1] = adjacent + (size_t)v * 128;
        aseg[2] = gl       + (size_t)ngid[v] * 128;

        fx4 acc[8];
        #pragma unroll
        for (int t = 0; t < 8; ++t) acc[t] = fx4{0.f, 0.f, 0.f, 0.f};

        // GEMM1: K=384, 12 k-steps, depth-2 raw prefetch
        fx4 buf[2][2];
        ld8(aseg[0] + qo,      buf[0][0], buf[0][1]);
        ld8(aseg[0] + 32 + qo, buf[1][0], buf[1][1]);
        #pragma unroll
        for (int ks = 0; ks < 12; ++ks) {
            bf16x8 a = cvt8(buf[ks & 1][0], buf[ks & 1][1]);
            if (ks < 10) {
                const int kn = ks + 2;
                ld8(aseg[kn >> 2] + ((kn & 3) << 5) + qo, buf[ks & 1][0], buf[ks & 1][1]);
            }
            #pragma unroll
            for (int t = 0; t < 8; ++t)
                acc[t] = mfma16(a, W1v[(t * 12 + ks) * 64 + lane], acc[t]);
        }

        #pragma unroll
        for (int t = 0; t < 8; ++t) {
            float bv = b1[t * 16 + m];
            #pragma unroll
            for (int r = 0; r < 4; ++r)
                s_H[wave][q * 4 + r][t * 16 + m] = (__bf16)fmaxf(acc[t][r] + bv, 0.f);
        }

        #pragma unroll
        for (int t = 0; t < 8; ++t) acc[t] = fx4{0.f, 0.f, 0.f, 0.f};

        #pragma unroll
        for (int ks = 0; ks < 4; ++ks) {
            bf16x8 a = *(const bf16x8*)&s_H[wave][m][ks * 32 + qo];
            #pragma unroll
            for (int t = 0; t < 8; ++t)
                acc[t] = mfma16(a, W2v[(t * 4 + ks) * 64 + lane], acc[t]);
        }

        const int vr0 = nblock + wbase + p * 16 + q * 4;
        int gd[4];
        #pragma unroll
        for (int r = 0; r < 4; ++r) gd[r] = ngid[vr0 + r];
        const bool sameg = (gd[0] == gd[3]);
        const int rel0 = gd[0] - g0;

        #pragma unroll
        for (int t = 0; t < 8; ++t) {
            const int col = t * 16 + m;
            const float bv = b2[col];
            float usum = 0.f;
            #pragma unroll
            for (int r = 0; r < 4; ++r) {
                const size_t vg = (size_t)(vr0 + r);
                float u = acc[t][r] + bv;
                out_nodes[vg * 128 + col] = nodes[vg * 128 + col] + mres * u;
                if (sameg) usum += u;
                else {
                    int rel = gd[r] - g0;
                    if (rel < 4) atomicAdd(&s_agg[rel * 128 + col], u);
                    else         unsafeAtomicAdd(&node_agg[gd[r] * 128 + col], u);
                }
            }
            if (sameg) {
                if (rel0 < 4) atomicAdd(&s_agg[rel0 * 128 + col], usum);
                else          unsafeAtomicAdd(&node_agg[gd[0] * 128 + col], usum);
            }
        }
    }

    __syncthreads();
    for (int i = tid; i < 4 * 128; i += 256) {
        float v = s_agg[i];
        if (v != 0.f)
            unsafeAtomicAdd(&node_agg[(g0 + (i >> 7)) * 128 + (i & 127)], v);
    }
}

// ---- global block: tiny MLP in fp32, 16 blocks x 128 threads ----
__global__ void gn_global_kernel(
    const float* __restrict__ gl,
    const float* __restrict__ gW1, const float* __restrict__ gb1,
    const float* __restrict__ gW2, const float* __restrict__ gb2,
    const float* __restrict__ rn_w,
    const float* __restrict__ node_agg, const float* __restrict__ edge_agg,
    float* __restrict__ out_gl)
{
    __shared__ float s_x[384];
    __shared__ float s_h[128];
    const int row = blockIdx.x, t = threadIdx.x;

    s_x[t]       = node_agg[row * 128 + t];
    s_x[128 + t] = edge_agg[row * 128 + t];
    s_x[256 + t] = gl[row * 128 + t];
    __syncthreads();

    float acc = gb1[t];
    for (int k = 0; k < 384; ++k) acc += s_x[k] * gW1[k * 128 + t];
    s_h[t] = fmaxf(acc, 0.f);
    __syncthreads();

    float acc2 = gb2[t];
    for (int k = 0; k < 128; ++k) acc2 += s_h[k] * gW2[k * 128 + t];
    const float mres = log1pf(expf(rn_w[0]));
    out_gl[row * 128 + t] = gl[row * 128 + t] + mres * acc2;
}

extern "C" void kernel_launch(void* const* d_in, const int* in_sizes, int n_in,
                              void* d_out, int out_size, void* d_ws, size_t ws_size,
                              hipStream_t stream)
{
    const float* nodes = (const float*)d_in[0];
    const float* edges = (const float*)d_in[1];
    const float* gl    = (const float*)d_in[2];
    const float* eW1   = (const float*)d_in[3];
    const float* eb1   = (const float*)d_in[4];
    const float* eW2   = (const float*)d_in[5];
    const float* eb2   = (const float*)d_in[6];
    const float* nW1   = (const float*)d_in[7];
    const float* nb1   = (const float*)d_in[8];
    const float* nW2   = (const float*)d_in[9];
    const float* nb2   = (const float*)d_in[10];
    const float* gW1   = (const float*)d_in[11];
    const float* gb1   = (const float*)d_in[12];
    const float* gW2   = (const float*)d_in[13];
    const float* gb2   = (const float*)d_in[14];
    const float* rn_w  = (const float*)d_in[15];
    const int* receivers = (const int*)d_in[16];
    const int* senders   = (const int*)d_in[17];
    const int* ngid      = (const int*)d_in[18];
    const int* egid      = (const int*)d_in[19];

    char* ws = (char*)d_ws;
    __bf16* eW1sw    = (__bf16*)(ws + 0);                // 131072 B
    __bf16* eW2sw    = (__bf16*)(ws + 131072);           // 32768 B
    __bf16* nW1sw    = (__bf16*)(ws + 163840);           // 98304 B
    __bf16* nW2sw    = (__bf16*)(ws + 262144);           // 32768 B
    float*  edge_agg = (float*)(ws + 294912);            // 8192 B
    float*  node_agg = (float*)(ws + 303104);            // 8192 B
    float*  adjacent = (float*)(ws + 311296);            // 67108864 B

    float* out_nodes = (float*)d_out;
    float* out_edges = out_nodes + (size_t)N_NODES * 128;
    float* out_gl    = out_edges + (size_t)N_EDGES * 128;

    // zero aggs + adjacent (ws is poisoned 0xAA before every launch)
    hipMemsetAsync(ws + 294912, 0, (size_t)16384 + 67108864, stream);

    gn_swizzle<<<dim3(256), dim3(256), 0, stream>>>(eW1, eW1sw, 16);
    gn_swizzle<<<dim3(64),  dim3(256), 0, stream>>>(eW2, eW2sw, 4);
    gn_swizzle<<<dim3(192), dim3(256), 0, stream>>>(nW1, nW1sw, 12);
    gn_swizzle<<<dim3(64),  dim3(256), 0, stream>>>(nW2, nW2sw, 4);

    gn_edge_kernel<<<dim3(N_EDGES / 128), dim3(256), 0, stream>>>(
        nodes, edges, gl, eW1sw, eb1, eW2sw, eb2, rn_w,
        senders, receivers, egid, out_edges, adjacent, edge_agg);

    gn_node_kernel<<<dim3(N_NODES / 128), dim3(256), 0, stream>>>(
        nodes, gl, nW1sw, nb1, nW2sw, nb2, rn_w,
        ngid, adjacent, out_nodes, node_agg);

    gn_global_kernel<<<dim3(NBATCH), dim3(128), 0, stream>>>(
        gl, gW1, gb1, gW2, gb2, rn_w, node_agg, edge_agg, out_gl);
}

// Round 3
// 1477.879 us; speedup vs baseline: 1.4339x; 1.3181x over previous
//
#include <hip/hip_runtime.h>
#include <hip/hip_bf16.h>

#define N_NODES 131072
#define N_EDGES 262144
#define NBATCH  16

typedef __attribute__((ext_vector_type(8))) __bf16 bf16x8;
typedef __attribute__((ext_vector_type(4))) float  fx4;

__device__ __forceinline__ fx4 mfma16(bf16x8 a, bf16x8 b, fx4 c) {
    return __builtin_amdgcn_mfma_f32_16x16x32_bf16(a, b, c, 0, 0, 0);
}

__device__ __forceinline__ void ld8(const float* p, fx4& x, fx4& y) {
    const fx4* q = (const fx4*)p;
    x = q[0]; y = q[1];
}
__device__ __forceinline__ bf16x8 cvt8(fx4 a, fx4 b) {
    bf16x8 r;
    r[0] = (__bf16)a[0]; r[1] = (__bf16)a[1]; r[2] = (__bf16)a[2]; r[3] = (__bf16)a[3];
    r[4] = (__bf16)b[0]; r[5] = (__bf16)b[1]; r[6] = (__bf16)b[2]; r[7] = (__bf16)b[3];
    return r;
}

// ---- rearrange row-major fp32 W[K][128] into bf16 MFMA B-operand order ----
// consumer reads bf16x8 at ((t*KS+ks)*64+lane):
//   B[k = ks*32 + (lane>>4)*8 + j][n = t*16 + (lane&15)]
__global__ void gn_swizzle(const float* __restrict__ src, __bf16* __restrict__ dst, int KS)
{
    int idx = blockIdx.x * 256 + threadIdx.x;
    int total = KS * 32 * 128;
    if (idx >= total) return;
    int j    = idx & 7;
    int lane = (idx >> 3) & 63;
    int rem  = idx >> 9;
    int ks   = rem % KS;
    int t    = rem / KS;
    int n = t * 16 + (lane & 15);
    int k = ks * 32 + ((lane >> 4) << 3) + j;
    dst[idx] = (__bf16)src[k * 128 + n];
}

// ---- edge block: u = MLP(concat(edges, nodes[send], nodes[recv], gl[gid])) ----
// Two sequential 16-row passes per wave, depth-2 A prefetch, wave-private s_H
// (no inter-GEMM barrier). LDS ~19.5 KB -> 8 blocks/CU by LDS.
// NO waves-per-EU launch bound: rounds 1-2 proved any cap ((256,6)->VGPR 40,
// (256,4)->arch 64) forces accumulator spill to scratch (+2.5 GB HBM traffic).
// Unbounded alloc (~92-110 VGPR) -> no spill, occupancy VGPR-bound ~5 waves/SIMD.
__global__ __launch_bounds__(256) void gn_edge_kernel(
    const float* __restrict__ nodes, const float* __restrict__ edges,
    const float* __restrict__ gl,
    const __bf16* __restrict__ W1sw, const float* __restrict__ b1,
    const __bf16* __restrict__ W2sw, const float* __restrict__ b2,
    const float* __restrict__ rn_w,
    const int* __restrict__ senders, const int* __restrict__ receivers,
    const int* __restrict__ egid,
    float* __restrict__ out_edges,
    float* __restrict__ adjacent,
    float* __restrict__ edge_agg)
{
    __shared__ __align__(16) __bf16 s_H[4][16][136];   // 17408 B, wave-private slices
    __shared__ float s_agg[4 * 128];                   // block spans <=4 graphs (sorted gid)

    const int tid  = threadIdx.x;
    const int wave = tid >> 6, lane = tid & 63;
    const int m = lane & 15, q = lane >> 4;
    const int qo = q << 3;
    const int eblock = blockIdx.x * 128;
    const int wbase  = wave * 32;
    const int g0 = egid[eblock];                       // min gid in block (sorted)

    for (int i = tid; i < 4 * 128; i += 256) s_agg[i] = 0.f;
    __syncthreads();

    const bf16x8* W1v = (const bf16x8*)W1sw;
    const bf16x8* W2v = (const bf16x8*)W2sw;
    const float mres = log1pf(expf(rn_w[0]));

    #pragma unroll 1
    for (int p = 0; p < 2; ++p) {
        // ---- this lane's A-row (row m of the 16-row pass tile) ----
        const int e = eblock + wbase + p * 16 + m;
        const float* aseg[4];
        aseg[0] = edges + (size_t)e * 128;
        aseg[1] = nodes + (size_t)senders[e]   * 128;
        aseg[2] = nodes + (size_t)receivers[e] * 128;
        aseg[3] = gl    + (size_t)egid[e]      * 128;

        fx4 acc[8];
        #pragma unroll
        for (int t = 0; t < 8; ++t) acc[t] = fx4{0.f, 0.f, 0.f, 0.f};

        // GEMM1: K=512, 16 k-steps of 32, depth-2 raw prefetch
        fx4 buf[2][2];
        ld8(aseg[0] + qo,      buf[0][0], buf[0][1]);   // ks=0
        ld8(aseg[0] + 32 + qo, buf[1][0], buf[1][1]);   // ks=1
        #pragma unroll
        for (int ks = 0; ks < 16; ++ks) {
            bf16x8 a = cvt8(buf[ks & 1][0], buf[ks & 1][1]);
            if (ks < 14) {
                const int kn = ks + 2;
                ld8(aseg[kn >> 2] + ((kn & 3) << 5) + qo, buf[ks & 1][0], buf[ks & 1][1]);
            }
            #pragma unroll
            for (int t = 0; t < 8; ++t)
                acc[t] = mfma16(a, W1v[(t * 16 + ks) * 64 + lane], acc[t]);
        }

        // bias + relu -> H (bf16) in wave-private LDS slice. C/D map: col=m, row=q*4+r
        #pragma unroll
        for (int t = 0; t < 8; ++t) {
            float bv = b1[t * 16 + m];
            #pragma unroll
            for (int r = 0; r < 4; ++r)
                s_H[wave][q * 4 + r][t * 16 + m] = (__bf16)fmaxf(acc[t][r] + bv, 0.f);
        }
        // no __syncthreads: slice is wave-private; per-wave DS ordering suffices

        #pragma unroll
        for (int t = 0; t < 8; ++t) acc[t] = fx4{0.f, 0.f, 0.f, 0.f};

        // GEMM2: K=128, 4 k-steps
        #pragma unroll
        for (int ks = 0; ks < 4; ++ks) {
            bf16x8 a = *(const bf16x8*)&s_H[wave][m][ks * 32 + qo];
            #pragma unroll
            for (int t = 0; t < 8; ++t)
                acc[t] = mfma16(a, W2v[(t * 4 + ks) * 64 + lane], acc[t]);
        }

        // epilogue: lane (q,m) owns rows q*4+r of this pass tile
        const int er0 = eblock + wbase + p * 16 + q * 4;
        int rcv[4], gd[4];
        #pragma unroll
        for (int r = 0; r < 4; ++r) {
            rcv[r] = receivers[er0 + r];
            gd[r]  = egid[er0 + r];
        }
        const bool sameg = (gd[0] == gd[3]);
        const int rel0 = gd[0] - g0;

        #pragma unroll
        for (int t = 0; t < 8; ++t) {
            const int col = t * 16 + m;
            const float bv = b2[col];
            float usum = 0.f;
            #pragma unroll
            for (int r = 0; r < 4; ++r) {
                const size_t eg = (size_t)(er0 + r);
                float u = acc[t][r] + bv;
                out_edges[eg * 128 + col] = edges[eg * 128 + col] + mres * u;
                unsafeAtomicAdd(&adjacent[(size_t)rcv[r] * 128 + col], u);
                if (sameg) usum += u;
                else {
                    int rel = gd[r] - g0;
                    if (rel < 4) atomicAdd(&s_agg[rel * 128 + col], u);
                    else         unsafeAtomicAdd(&edge_agg[gd[r] * 128 + col], u);
                }
            }
            if (sameg) {
                if (rel0 < 4) atomicAdd(&s_agg[rel0 * 128 + col], usum);
                else          unsafeAtomicAdd(&edge_agg[gd[0] * 128 + col], usum);
            }
        }
    }

    __syncthreads();
    for (int i = tid; i < 4 * 128; i += 256) {
        float v = s_agg[i];
        if (v != 0.f)
            unsafeAtomicAdd(&edge_agg[(g0 + (i >> 7)) * 128 + (i & 127)], v);
    }
}

// ---- node block: u = MLP(concat(nodes, adjacent, gl[gid])) ----
__global__ __launch_bounds__(256) void gn_node_kernel(
    const float* __restrict__ nodes,
    const float* __restrict__ gl,
    const __bf16* __restrict__ W1sw, const float* __restrict__ b1,
    const __bf16* __restrict__ W2sw, const float* __restrict__ b2,
    const float* __restrict__ rn_w,
    const int* __restrict__ ngid,
    const float* __restrict__ adjacent,
    float* __restrict__ out_nodes,
    float* __restrict__ node_agg)
{
    __shared__ __align__(16) __bf16 s_H[4][16][136];
    __shared__ float s_agg[4 * 128];

    const int tid  = threadIdx.x;
    const int wave = tid >> 6, lane = tid & 63;
    const int m = lane & 15, q = lane >> 4;
    const int qo = q << 3;
    const int nblock = blockIdx.x * 128;
    const int wbase  = wave * 32;
    const int g0 = ngid[nblock];

    for (int i = tid; i < 4 * 128; i += 256) s_agg[i] = 0.f;
    __syncthreads();

    const bf16x8* W1v = (const bf16x8*)W1sw;
    const bf16x8* W2v = (const bf16x8*)W2sw;
    const float mres = log1pf(expf(rn_w[0]));

    #pragma unroll 1
    for (int p = 0; p < 2; ++p) {
        const int v = nblock + wbase + p * 16 + m;
        const float* aseg[3];
        aseg[0] = nodes    + (size_t)v * 128;
        aseg[1] = adjacent + (size_t)v * 128;
        aseg[2] = gl       + (size_t)ngid[v] * 128;

        fx4 acc[8];
        #pragma unroll
        for (int t = 0; t < 8; ++t) acc[t] = fx4{0.f, 0.f, 0.f, 0.f};

        // GEMM1: K=384, 12 k-steps, depth-2 raw prefetch
        fx4 buf[2][2];
        ld8(aseg[0] + qo,      buf[0][0], buf[0][1]);
        ld8(aseg[0] + 32 + qo, buf[1][0], buf[1][1]);
        #pragma unroll
        for (int ks = 0; ks < 12; ++ks) {
            bf16x8 a = cvt8(buf[ks & 1][0], buf[ks & 1][1]);
            if (ks < 10) {
                const int kn = ks + 2;
                ld8(aseg[kn >> 2] + ((kn & 3) << 5) + qo, buf[ks & 1][0], buf[ks & 1][1]);
            }
            #pragma unroll
            for (int t = 0; t < 8; ++t)
                acc[t] = mfma16(a, W1v[(t * 12 + ks) * 64 + lane], acc[t]);
        }

        #pragma unroll
        for (int t = 0; t < 8; ++t) {
            float bv = b1[t * 16 + m];
            #pragma unroll
            for (int r = 0; r < 4; ++r)
                s_H[wave][q * 4 + r][t * 16 + m] = (__bf16)fmaxf(acc[t][r] + bv, 0.f);
        }

        #pragma unroll
        for (int t = 0; t < 8; ++t) acc[t] = fx4{0.f, 0.f, 0.f, 0.f};

        #pragma unroll
        for (int ks = 0; ks < 4; ++ks) {
            bf16x8 a = *(const bf16x8*)&s_H[wave][m][ks * 32 + qo];
            #pragma unroll
            for (int t = 0; t < 8; ++t)
                acc[t] = mfma16(a, W2v[(t * 4 + ks) * 64 + lane], acc[t]);
        }

        const int vr0 = nblock + wbase + p * 16 + q * 4;
        int gd[4];
        #pragma unroll
        for (int r = 0; r < 4; ++r) gd[r] = ngid[vr0 + r];
        const bool sameg = (gd[0] == gd[3]);
        const int rel0 = gd[0] - g0;

        #pragma unroll
        for (int t = 0; t < 8; ++t) {
            const int col = t * 16 + m;
            const float bv = b2[col];
            float usum = 0.f;
            #pragma unroll
            for (int r = 0; r < 4; ++r) {
                const size_t vg = (size_t)(vr0 + r);
                float u = acc[t][r] + bv;
                out_nodes[vg * 128 + col] = nodes[vg * 128 + col] + mres * u;
                if (sameg) usum += u;
                else {
                    int rel = gd[r] - g0;
                    if (rel < 4) atomicAdd(&s_agg[rel * 128 + col], u);
                    else         unsafeAtomicAdd(&node_agg[gd[r] * 128 + col], u);
                }
            }
            if (sameg) {
                if (rel0 < 4) atomicAdd(&s_agg[rel0 * 128 + col], usum);
                else          unsafeAtomicAdd(&node_agg[gd[0] * 128 + col], usum);
            }
        }
    }

    __syncthreads();
    for (int i = tid; i < 4 * 128; i += 256) {
        float v = s_agg[i];
        if (v != 0.f)
            unsafeAtomicAdd(&node_agg[(g0 + (i >> 7)) * 128 + (i & 127)], v);
    }
}

// ---- global block: tiny MLP in fp32, 16 blocks x 128 threads ----
__global__ void gn_global_kernel(
    const float* __restrict__ gl,
    const float* __restrict__ gW1, const float* __restrict__ gb1,
    const float* __restrict__ gW2, const float* __restrict__ gb2,
    const float* __restrict__ rn_w,
    const float* __restrict__ node_agg, const float* __restrict__ edge_agg,
    float* __restrict__ out_gl)
{
    __shared__ float s_x[384];
    __shared__ float s_h[128];
    const int row = blockIdx.x, t = threadIdx.x;

    s_x[t]       = node_agg[row * 128 + t];
    s_x[128 + t] = edge_agg[row * 128 + t];
    s_x[256 + t] = gl[row * 128 + t];
    __syncthreads();

    float acc = gb1[t];
    for (int k = 0; k < 384; ++k) acc += s_x[k] * gW1[k * 128 + t];
    s_h[t] = fmaxf(acc, 0.f);
    __syncthreads();

    float acc2 = gb2[t];
    for (int k = 0; k < 128; ++k) acc2 += s_h[k] * gW2[k * 128 + t];
    const float mres = log1pf(expf(rn_w[0]));
    out_gl[row * 128 + t] = gl[row * 128 + t] + mres * acc2;
}

extern "C" void kernel_launch(void* const* d_in, const int* in_sizes, int n_in,
                              void* d_out, int out_size, void* d_ws, size_t ws_size,
                              hipStream_t stream)
{
    const float* nodes = (const float*)d_in[0];
    const float* edges = (const float*)d_in[1];
    const float* gl    = (const float*)d_in[2];
    const float* eW1   = (const float*)d_in[3];
    const float* eb1   = (const float*)d_in[4];
    const float* eW2   = (const float*)d_in[5];
    const float* eb2   = (const float*)d_in[6];
    const float* nW1   = (const float*)d_in[7];
    const float* nb1   = (const float*)d_in[8];
    const float* nW2   = (const float*)d_in[9];
    const float* nb2   = (const float*)d_in[10];
    const float* gW1   = (const float*)d_in[11];
    const float* gb1   = (const float*)d_in[12];
    const float* gW2   = (const float*)d_in[13];
    const float* gb2   = (const float*)d_in[14];
    const float* rn_w  = (const float*)d_in[15];
    const int* receivers = (const int*)d_in[16];
    const int* senders   = (const int*)d_in[17];
    const int* ngid      = (const int*)d_in[18];
    const int* egid      = (const int*)d_in[19];

    char* ws = (char*)d_ws;
    __bf16* eW1sw    = (__bf16*)(ws + 0);                // 131072 B
    __bf16* eW2sw    = (__bf16*)(ws + 131072);           // 32768 B
    __bf16* nW1sw    = (__bf16*)(ws + 163840);           // 98304 B
    __bf16* nW2sw    = (__bf16*)(ws + 262144);           // 32768 B
    float*  edge_agg = (float*)(ws + 294912);            // 8192 B
    float*  node_agg = (float*)(ws + 303104);            // 8192 B
    float*  adjacent = (float*)(ws + 311296);            // 67108864 B

    float* out_nodes = (float*)d_out;
    float* out_edges = out_nodes + (size_t)N_NODES * 128;
    float* out_gl    = out_edges + (size_t)N_EDGES * 128;

    // zero aggs + adjacent (ws is poisoned 0xAA before every launch)
    hipMemsetAsync(ws + 294912, 0, (size_t)16384 + 67108864, stream);

    gn_swizzle<<<dim3(256), dim3(256), 0, stream>>>(eW1, eW1sw, 16);
    gn_swizzle<<<dim3(64),  dim3(256), 0, stream>>>(eW2, eW2sw, 4);
    gn_swizzle<<<dim3(192), dim3(256), 0, stream>>>(nW1, nW1sw, 12);
    gn_swizzle<<<dim3(64),  dim3(256), 0, stream>>>(nW2, nW2sw, 4);

    gn_edge_kernel<<<dim3(N_EDGES / 128), dim3(256), 0, stream>>>(
        nodes, edges, gl, eW1sw, eb1, eW2sw, eb2, rn_w,
        senders, receivers, egid, out_edges, adjacent, edge_agg);

    gn_node_kernel<<<dim3(N_NODES / 128), dim3(256), 0, stream>>>(
        nodes, gl, nW1sw, nb1, nW2sw, nb2, rn_w,
        ngid, adjacent, out_nodes, node_agg);

    gn_global_kernel<<<dim3(NBATCH), dim3(128), 0, stream>>>(
        gl, gW1, gb1, gW2, gb2, rn_w, node_agg, edge_agg, out_gl);
}

// Round 4
// 1470.525 us; speedup vs baseline: 1.4411x; 1.0050x over previous
//
#include <hip/hip_runtime.h>
#include <hip/hip_bf16.h>

#define N_NODES 131072
#define N_EDGES 262144
#define NBATCH  16

typedef __attribute__((ext_vector_type(8))) __bf16 bf16x8;
typedef __attribute__((ext_vector_type(4))) float  fx4;

__device__ __forceinline__ fx4 mfma16(bf16x8 a, bf16x8 b, fx4 c) {
    return __builtin_amdgcn_mfma_f32_16x16x32_bf16(a, b, c, 0, 0, 0);
}

// load 8 consecutive fp32, convert to bf16x8 (A-fragment k-slice) — JIT style,
// identical to the round-0 body that compiled to 92 VGPR with zero spill.
__device__ __forceinline__ bf16x8 load_row8(const float* p) {
    const fx4* q = (const fx4*)p;
    fx4 a = q[0], b = q[1];
    bf16x8 r;
    r[0] = (__bf16)a[0]; r[1] = (__bf16)a[1]; r[2] = (__bf16)a[2]; r[3] = (__bf16)a[3];
    r[4] = (__bf16)b[0]; r[5] = (__bf16)b[1]; r[6] = (__bf16)b[2]; r[7] = (__bf16)b[3];
    return r;
}

// phase fence: scheduling-region boundary so the compiler cannot balloon live
// ranges across phases (rounds 1-3: without fences VGPR went 40/64/256 with
// 0.5-2.5 GB of scratch spill traffic; round 0's in-body __syncthreads were
// acting as these fences).
__device__ __forceinline__ void phase_fence() {
    __builtin_amdgcn_sched_barrier(0);
}

// ---- rearrange row-major fp32 W[K][128] into bf16 MFMA B-operand order ----
// consumer reads bf16x8 at ((t*KS+ks)*64+lane):
//   B[k = ks*32 + (lane>>4)*8 + j][n = t*16 + (lane&15)]
__global__ void gn_swizzle(const float* __restrict__ src, __bf16* __restrict__ dst, int KS)
{
    int idx = blockIdx.x * 256 + threadIdx.x;
    int total = KS * 32 * 128;
    if (idx >= total) return;
    int j    = idx & 7;
    int lane = (idx >> 3) & 63;
    int rem  = idx >> 9;
    int ks   = rem % KS;
    int t    = rem / KS;
    int n = t * 16 + (lane & 15);
    int k = ks * 32 + ((lane >> 4) << 3) + j;
    dst[idx] = (__bf16)src[k * 128 + n];
}

// ---- edge block: u = MLP(concat(edges, nodes[send], nodes[recv], gl[gid])) ----
// Two sequential 16-row passes per wave; JIT A-loads; wave-private s_H slice;
// sched_barrier(0) phase fences. LDS 19456 B -> 8 blocks/CU by LDS; no
// waves-per-EU bound (any cap forces spill, rounds 1-2).
__global__ __launch_bounds__(256) void gn_edge_kernel(
    const float* __restrict__ nodes, const float* __restrict__ edges,
    const float* __restrict__ gl,
    const __bf16* __restrict__ W1sw, const float* __restrict__ b1,
    const __bf16* __restrict__ W2sw, const float* __restrict__ b2,
    const float* __restrict__ rn_w,
    const int* __restrict__ senders, const int* __restrict__ receivers,
    const int* __restrict__ egid,
    float* __restrict__ out_edges,
    float* __restrict__ adjacent,
    float* __restrict__ edge_agg)
{
    __shared__ __align__(16) __bf16 s_H[4][16][136];   // 17408 B, wave-private slices
    __shared__ float s_agg[4 * 128];                   // block spans <=4 graphs (sorted gid)

    const int tid  = threadIdx.x;
    const int wave = tid >> 6, lane = tid & 63;
    const int m = lane & 15, q = lane >> 4;
    const int qo = q << 3;
    const int eblock = blockIdx.x * 128;
    const int wbase  = wave * 32;
    const int g0 = egid[eblock];                       // min gid in block (sorted)

    for (int i = tid; i < 4 * 128; i += 256) s_agg[i] = 0.f;
    __syncthreads();

    const bf16x8* W1v = (const bf16x8*)W1sw;
    const bf16x8* W2v = (const bf16x8*)W2sw;
    const float mres = log1pf(expf(rn_w[0]));

    #pragma unroll 1
    for (int p = 0; p < 2; ++p) {
        // ---- this lane's A-row (row m of the 16-row pass tile) ----
        const int e = eblock + wbase + p * 16 + m;
        const float* aseg[4];
        aseg[0] = edges + (size_t)e * 128;
        aseg[1] = nodes + (size_t)senders[e]   * 128;
        aseg[2] = nodes + (size_t)receivers[e] * 128;
        aseg[3] = gl    + (size_t)egid[e]      * 128;

        fx4 acc[8];
        #pragma unroll
        for (int t = 0; t < 8; ++t) acc[t] = fx4{0.f, 0.f, 0.f, 0.f};

        // GEMM1: K=512, 16 k-steps of 32, JIT loads
        #pragma unroll
        for (int ks = 0; ks < 16; ++ks) {
            const int seg  = ks >> 2;
            const int koff = ((ks & 3) << 5) + qo;
            bf16x8 a = load_row8(aseg[seg] + koff);
            #pragma unroll
            for (int t = 0; t < 8; ++t)
                acc[t] = mfma16(a, W1v[(t * 16 + ks) * 64 + lane], acc[t]);
        }
        phase_fence();

        // bias + relu -> H (bf16) in wave-private LDS slice. C/D map: col=m, row=q*4+r
        #pragma unroll
        for (int t = 0; t < 8; ++t) {
            float bv = b1[t * 16 + m];
            #pragma unroll
            for (int r = 0; r < 4; ++r)
                s_H[wave][q * 4 + r][t * 16 + m] = (__bf16)fmaxf(acc[t][r] + bv, 0.f);
        }
        phase_fence();
        // no __syncthreads: slice is wave-private; per-wave DS ordering suffices

        #pragma unroll
        for (int t = 0; t < 8; ++t) acc[t] = fx4{0.f, 0.f, 0.f, 0.f};

        // GEMM2: K=128, 4 k-steps
        #pragma unroll
        for (int ks = 0; ks < 4; ++ks) {
            bf16x8 a = *(const bf16x8*)&s_H[wave][m][ks * 32 + qo];
            #pragma unroll
            for (int t = 0; t < 8; ++t)
                acc[t] = mfma16(a, W2v[(t * 4 + ks) * 64 + lane], acc[t]);
        }
        phase_fence();

        // epilogue: lane (q,m) owns rows q*4+r of this pass tile
        const int er0 = eblock + wbase + p * 16 + q * 4;
        int rcv[4], gd[4];
        #pragma unroll
        for (int r = 0; r < 4; ++r) {
            rcv[r] = receivers[er0 + r];
            gd[r]  = egid[er0 + r];
        }
        const bool sameg = (gd[0] == gd[3]);
        const int rel0 = gd[0] - g0;

        #pragma unroll
        for (int t = 0; t < 8; ++t) {
            const int col = t * 16 + m;
            const float bv = b2[col];
            float usum = 0.f;
            #pragma unroll
            for (int r = 0; r < 4; ++r) {
                const size_t eg = (size_t)(er0 + r);
                float u = acc[t][r] + bv;
                out_edges[eg * 128 + col] = edges[eg * 128 + col] + mres * u;
                unsafeAtomicAdd(&adjacent[(size_t)rcv[r] * 128 + col], u);
                if (sameg) usum += u;
                else {
                    int rel = gd[r] - g0;
                    if (rel < 4) atomicAdd(&s_agg[rel * 128 + col], u);
                    else         unsafeAtomicAdd(&edge_agg[gd[r] * 128 + col], u);
                }
            }
            if (sameg) {
                if (rel0 < 4) atomicAdd(&s_agg[rel0 * 128 + col], usum);
                else          unsafeAtomicAdd(&edge_agg[gd[0] * 128 + col], usum);
            }
        }
        phase_fence();
    }

    __syncthreads();
    for (int i = tid; i < 4 * 128; i += 256) {
        float v = s_agg[i];
        if (v != 0.f)
            unsafeAtomicAdd(&edge_agg[(g0 + (i >> 7)) * 128 + (i & 127)], v);
    }
}

// ---- node block: u = MLP(concat(nodes, adjacent, gl[gid])) ----
__global__ __launch_bounds__(256) void gn_node_kernel(
    const float* __restrict__ nodes,
    const float* __restrict__ gl,
    const __bf16* __restrict__ W1sw, const float* __restrict__ b1,
    const __bf16* __restrict__ W2sw, const float* __restrict__ b2,
    const float* __restrict__ rn_w,
    const int* __restrict__ ngid,
    const float* __restrict__ adjacent,
    float* __restrict__ out_nodes,
    float* __restrict__ node_agg)
{
    __shared__ __align__(16) __bf16 s_H[4][16][136];
    __shared__ float s_agg[4 * 128];

    const int tid  = threadIdx.x;
    const int wave = tid >> 6, lane = tid & 63;
    const int m = lane & 15, q = lane >> 4;
    const int qo = q << 3;
    const int nblock = blockIdx.x * 128;
    const int wbase  = wave * 32;
    const int g0 = ngid[nblock];

    for (int i = tid; i < 4 * 128; i += 256) s_agg[i] = 0.f;
    __syncthreads();

    const bf16x8* W1v = (const bf16x8*)W1sw;
    const bf16x8* W2v = (const bf16x8*)W2sw;
    const float mres = log1pf(expf(rn_w[0]));

    #pragma unroll 1
    for (int p = 0; p < 2; ++p) {
        const int v = nblock + wbase + p * 16 + m;
        const float* aseg[3];
        aseg[0] = nodes    + (size_t)v * 128;
        aseg[1] = adjacent + (size_t)v * 128;
        aseg[2] = gl       + (size_t)ngid[v] * 128;

        fx4 acc[8];
        #pragma unroll
        for (int t = 0; t < 8; ++t) acc[t] = fx4{0.f, 0.f, 0.f, 0.f};

        // GEMM1: K=384, 12 k-steps, JIT loads
        #pragma unroll
        for (int ks = 0; ks < 12; ++ks) {
            const int seg  = ks >> 2;
            const int koff = ((ks & 3) << 5) + qo;
            bf16x8 a = load_row8(aseg[seg] + koff);
            #pragma unroll
            for (int t = 0; t < 8; ++t)
                acc[t] = mfma16(a, W1v[(t * 12 + ks) * 64 + lane], acc[t]);
        }
        phase_fence();

        #pragma unroll
        for (int t = 0; t < 8; ++t) {
            float bv = b1[t * 16 + m];
            #pragma unroll
            for (int r = 0; r < 4; ++r)
                s_H[wave][q * 4 + r][t * 16 + m] = (__bf16)fmaxf(acc[t][r] + bv, 0.f);
        }
        phase_fence();

        #pragma unroll
        for (int t = 0; t < 8; ++t) acc[t] = fx4{0.f, 0.f, 0.f, 0.f};

        #pragma unroll
        for (int ks = 0; ks < 4; ++ks) {
            bf16x8 a = *(const bf16x8*)&s_H[wave][m][ks * 32 + qo];
            #pragma unroll
            for (int t = 0; t < 8; ++t)
                acc[t] = mfma16(a, W2v[(t * 4 + ks) * 64 + lane], acc[t]);
        }
        phase_fence();

        const int vr0 = nblock + wbase + p * 16 + q * 4;
        int gd[4];
        #pragma unroll
        for (int r = 0; r < 4; ++r) gd[r] = ngid[vr0 + r];
        const bool sameg = (gd[0] == gd[3]);
        const int rel0 = gd[0] - g0;

        #pragma unroll
        for (int t = 0; t < 8; ++t) {
            const int col = t * 16 + m;
            const float bv = b2[col];
            float usum = 0.f;
            #pragma unroll
            for (int r = 0; r < 4; ++r) {
                const size_t vg = (size_t)(vr0 + r);
                float u = acc[t][r] + bv;
                out_nodes[vg * 128 + col] = nodes[vg * 128 + col] + mres * u;
                if (sameg) usum += u;
                else {
                    int rel = gd[r] - g0;
                    if (rel < 4) atomicAdd(&s_agg[rel * 128 + col], u);
                    else         unsafeAtomicAdd(&node_agg[gd[r] * 128 + col], u);
                }
            }
            if (sameg) {
                if (rel0 < 4) atomicAdd(&s_agg[rel0 * 128 + col], usum);
                else          unsafeAtomicAdd(&node_agg[gd[0] * 128 + col], usum);
            }
        }
        phase_fence();
    }

    __syncthreads();
    for (int i = tid; i < 4 * 128; i += 256) {
        float v = s_agg[i];
        if (v != 0.f)
            unsafeAtomicAdd(&node_agg[(g0 + (i >> 7)) * 128 + (i & 127)], v);
    }
}

// ---- global block: tiny MLP in fp32, 16 blocks x 128 threads ----
__global__ void gn_global_kernel(
    const float* __restrict__ gl,
    const float* __restrict__ gW1, const float* __restrict__ gb1,
    const float* __restrict__ gW2, const float* __restrict__ gb2,
    const float* __restrict__ rn_w,
    const float* __restrict__ node_agg, const float* __restrict__ edge_agg,
    float* __restrict__ out_gl)
{
    __shared__ float s_x[384];
    __shared__ float s_h[128];
    const int row = blockIdx.x, t = threadIdx.x;

    s_x[t]       = node_agg[row * 128 + t];
    s_x[128 + t] = edge_agg[row * 128 + t];
    s_x[256 + t] = gl[row * 128 + t];
    __syncthreads();

    float acc = gb1[t];
    for (int k = 0; k < 384; ++k) acc += s_x[k] * gW1[k * 128 + t];
    s_h[t] = fmaxf(acc, 0.f);
    __syncthreads();

    float acc2 = gb2[t];
    for (int k = 0; k < 128; ++k) acc2 += s_h[k] * gW2[k * 128 + t];
    const float mres = log1pf(expf(rn_w[0]));
    out_gl[row * 128 + t] = gl[row * 128 + t] + mres * acc2;
}

extern "C" void kernel_launch(void* const* d_in, const int* in_sizes, int n_in,
                              void* d_out, int out_size, void* d_ws, size_t ws_size,
                              hipStream_t stream)
{
    const float* nodes = (const float*)d_in[0];
    const float* edges = (const float*)d_in[1];
    const float* gl    = (const float*)d_in[2];
    const float* eW1   = (const float*)d_in[3];
    const float* eb1   = (const float*)d_in[4];
    const float* eW2   = (const float*)d_in[5];
    const float* eb2   = (const float*)d_in[6];
    const float* nW1   = (const float*)d_in[7];
    const float* nb1   = (const float*)d_in[8];
    const float* nW2   = (const float*)d_in[9];
    const float* nb2   = (const float*)d_in[10];
    const float* gW1   = (const float*)d_in[11];
    const float* gb1   = (const float*)d_in[12];
    const float* gW2   = (const float*)d_in[13];
    const float* gb2   = (const float*)d_in[14];
    const float* rn_w  = (const float*)d_in[15];
    const int* receivers = (const int*)d_in[16];
    const int* senders   = (const int*)d_in[17];
    const int* ngid      = (const int*)d_in[18];
    const int* egid      = (const int*)d_in[19];

    char* ws = (char*)d_ws;
    __bf16* eW1sw    = (__bf16*)(ws + 0);                // 131072 B
    __bf16* eW2sw    = (__bf16*)(ws + 131072);           // 32768 B
    __bf16* nW1sw    = (__bf16*)(ws + 163840);           // 98304 B
    __bf16* nW2sw    = (__bf16*)(ws + 262144);           // 32768 B
    float*  edge_agg = (float*)(ws + 294912);            // 8192 B
    float*  node_agg = (float*)(ws + 303104);            // 8192 B
    float*  adjacent = (float*)(ws + 311296);            // 67108864 B

    float* out_nodes = (float*)d_out;
    float* out_edges = out_nodes + (size_t)N_NODES * 128;
    float* out_gl    = out_edges + (size_t)N_EDGES * 128;

    // zero aggs + adjacent (ws is poisoned 0xAA before every launch)
    hipMemsetAsync(ws + 294912, 0, (size_t)16384 + 67108864, stream);

    gn_swizzle<<<dim3(256), dim3(256), 0, stream>>>(eW1, eW1sw, 16);
    gn_swizzle<<<dim3(64),  dim3(256), 0, stream>>>(eW2, eW2sw, 4);
    gn_swizzle<<<dim3(192), dim3(256), 0, stream>>>(nW1, nW1sw, 12);
    gn_swizzle<<<dim3(64),  dim3(256), 0, stream>>>(nW2, nW2sw, 4);

    gn_edge_kernel<<<dim3(N_EDGES / 128), dim3(256), 0, stream>>>(
        nodes, edges, gl, eW1sw, eb1, eW2sw, eb2, rn_w,
        senders, receivers, egid, out_edges, adjacent, edge_agg);

    gn_node_kernel<<<dim3(N_NODES / 128), dim3(256), 0, stream>>>(
        nodes, gl, nW1sw, nb1, nW2sw, nb2, rn_w,
        ngid, adjacent, out_nodes, node_agg);

    gn_global_kernel<<<dim3(NBATCH), dim3(128), 0, stream>>>(
        gl, gW1, gb1, gW2, gb2, rn_w, node_agg, edge_agg, out_gl);
}